// Round 1
// baseline (3401.612 us; speedup 1.0000x reference)
//
#include <hip/hip_runtime.h>
#include <math.h>

#define NN 50000
#define NBB 256
#define DD 128
#define FF 16
#define EE 800000
#define RR 15
#define EPSV 1e-7f
#define CSPACE (5.0f/14.0f)

__device__ __forceinline__ float lrelu(float x){ return x >= 0.f ? x : 0.01f*x; }
__device__ __forceinline__ float sigmoidf_(float x){ return 1.f/(1.f+expf(-x)); }

// ---------------- transpose GRU weights for coalesced GEMV ----------------
__global__ void k_transpose(const float* __restrict__ Wih, const float* __restrict__ Whh,
                            float* __restrict__ WihT, float* __restrict__ WhhT){
    int i = blockIdx.x*256 + threadIdx.x;
    if (i < 384*256){ int k = i/256, j = i%256; WihT[j*384+k] = Wih[i]; }
    if (i < 384*128){ int k = i/128, j = i%128; WhhT[j*384+k] = Whh[i]; }
}

// ---------------- per-node: VN1/VN2/VN3 norms, phi3 gate -> vp, phi2 -> hpp ----------------
__global__ __launch_bounds__(256) void k_node_feats(
    const float* __restrict__ hA, const float* __restrict__ vA,
    const float* __restrict__ vn1W, const float* __restrict__ vn1U,
    const float* __restrict__ vn2W, const float* __restrict__ vn2U,
    const float* __restrict__ vn3W, const float* __restrict__ vn3U,
    const float* __restrict__ phi2W, const float* __restrict__ phi2b,
    const float* __restrict__ phi3W, const float* __restrict__ phi3b,
    float* __restrict__ vnorm1O, float* __restrict__ hppO, float* __restrict__ vpO)
{
    __shared__ float sVn[6][FF*FF];
    __shared__ float sP3[DD*FF];
    __shared__ float sP2[(DD+FF)*FF];
    __shared__ float sV[16][50];        // padded
    __shared__ float sH[16][DD+2];      // padded
    __shared__ float sVn2[16][FF];
    int tid = threadIdx.x;
    for (int i = tid; i < FF*FF; i += 256){
        sVn[0][i]=vn1W[i]; sVn[1][i]=vn1U[i]; sVn[2][i]=vn2W[i];
        sVn[3][i]=vn2U[i]; sVn[4][i]=vn3W[i]; sVn[5][i]=vn3U[i];
    }
    for (int i = tid; i < DD*FF; i += 256) sP3[i]=phi3W[i];
    for (int i = tid; i < (DD+FF)*FF; i += 256) sP2[i]=phi2W[i];
    int n0 = blockIdx.x*16;
    for (int i = tid; i < 16*FF*3; i += 256) sV[i/(FF*3)][i%(FF*3)] = vA[(size_t)n0*FF*3 + i];
    for (int i = tid; i < 16*DD; i += 256) sH[i/DD][i%DD] = hA[(size_t)n0*DD + i];
    __syncthreads();
    int t = tid >> 4, g = tid & 15;
    int n = n0 + t;
    const float* v = sV[t];
    float o0=0.f,o1=0.f,o2=0.f;
    float vn_norm0=0.f, vn_norm1v=0.f;
    #pragma unroll
    for (int m = 0; m < 3; ++m){
        const float* W = sVn[2*m]; const float* U = sVn[2*m+1];
        float q0=0,q1=0,q2=0,k0=0,k1=0,k2=0;
        #pragma unroll
        for (int ff = 0; ff < FF; ++ff){
            int f = (ff + g) & (FF-1);   // stagger to avoid LDS bank conflict
            float w = W[g*FF+f], u = U[g*FF+f];
            float v0=v[f*3],v1=v[f*3+1],v2=v[f*3+2];
            q0+=w*v0; q1+=w*v1; q2+=w*v2;
            k0+=u*v0; k1+=u*v1; k2+=u*v2;
        }
        float dot=q0*k0+q1*k1+q2*k2;
        float ksq=k0*k0+k1*k1+k2*k2+EPSV;
        float s = dot>=0.f?0.f:dot/ksq;
        o0=q0-s*k0; o1=q1-s*k1; o2=q2-s*k2;
        if (m==0) vn_norm0 = sqrtf(o0*o0+o1*o1+o2*o2) + EPSV;
        if (m==1) vn_norm1v = sqrtf(o0*o0+o1*o1+o2*o2) + EPSV;
    }
    vnorm1O[(size_t)n*FF+g] = vn_norm0;
    sVn2[t][g] = vn_norm1v;
    __syncthreads();
    float acc3 = phi3b[g];
    for (int i = 0; i < DD; ++i) acc3 += sH[t][i]*sP3[i*FF+g];
    float gate = lrelu(acc3);
    vpO[(size_t)n*FF*3 + g*3 + 0] = o0*gate;
    vpO[(size_t)n*FF*3 + g*3 + 1] = o1*gate;
    vpO[(size_t)n*FF*3 + g*3 + 2] = o2*gate;
    float acc2 = phi2b[g];
    for (int i = 0; i < DD; ++i) acc2 += sH[t][i]*sP2[i*FF+g];
    #pragma unroll
    for (int f = 0; f < FF; ++f) acc2 += sVn2[t][f]*sP2[(DD+f)*FF+g];
    hppO[(size_t)n*FF+g] = lrelu(acc2);
}

// ---------------- hp = lrelu([h_A, vnorm1] @ phi1_W + b) ----------------
__global__ __launch_bounds__(128) void k_hp(
    const float* __restrict__ hA, const float* __restrict__ vnorm1,
    const float* __restrict__ phi1W, const float* __restrict__ phi1b,
    float* __restrict__ hpO)
{
    __shared__ float sX[8][DD+FF];
    int tid = threadIdx.x;
    int n0 = blockIdx.x*8;
    for (int i = tid; i < 8*DD; i += 128) sX[i/DD][i%DD] = hA[(size_t)n0*DD + i];
    for (int i = tid; i < 8*FF; i += 128) sX[i/FF][DD + i%FF] = vnorm1[(size_t)n0*FF + i];
    __syncthreads();
    float b = phi1b[tid];
    float a[8];
    #pragma unroll
    for (int t = 0; t < 8; ++t) a[t] = b;
    for (int i = 0; i < DD+FF; ++i){
        float w = phi1W[i*DD + tid];
        #pragma unroll
        for (int t = 0; t < 8; ++t) a[t] += sX[t][i]*w;
    }
    #pragma unroll
    for (int t = 0; t < 8; ++t) hpO[(size_t)(n0+t)*DD+tid] = lrelu(a[t]);
}

// ---------------- kk = lrelu(h_B@Wk), vv = h_B@Wv + bv ----------------
__global__ __launch_bounds__(128) void k_kv(
    const float* __restrict__ hB, const float* __restrict__ Wk,
    const float* __restrict__ Wv, const float* __restrict__ bv,
    float* __restrict__ kkO, float* __restrict__ vvO)
{
    __shared__ float sB[DD];
    int b = blockIdx.x, j = threadIdx.x;
    sB[j] = hB[(size_t)b*DD + j];
    __syncthreads();
    float ak = 0.f, av = bv[j];
    for (int i = 0; i < DD; ++i){
        float h = sB[i];
        ak += h*Wk[i*DD+j];
        av += h*Wv[i*DD+j];
    }
    kkO[(size_t)b*DD+j] = lrelu(ak);
    vvO[(size_t)b*DD+j] = av;
}

// ---------------- fused cross-attention: q-proj, scores, softmax, PV ----------------
__global__ __launch_bounds__(256) void k_attn(
    const float* __restrict__ hA, const float* __restrict__ Wq,
    const float* __restrict__ kk, const float* __restrict__ vv,
    const float* __restrict__ mask, float* __restrict__ attnO)
{
    __shared__ float sH[8][DD];
    __shared__ float sQ[8][DD];
    __shared__ float sS[8][NBB];
    __shared__ float sRed[8];
    __shared__ float sSum[8];
    int tid = threadIdx.x;
    int n0 = blockIdx.x*8;
    for (int i = tid; i < 8*DD; i += 256) sH[i/DD][i%DD] = hA[(size_t)n0*DD + i];
    __syncthreads();
    int j = tid & 127, half = tid >> 7;
    {
        float a0=0,a1=0,a2=0,a3=0;
        for (int i = 0; i < DD; ++i){
            float w = Wq[i*DD+j];
            a0 += sH[half*4+0][i]*w;
            a1 += sH[half*4+1][i]*w;
            a2 += sH[half*4+2][i]*w;
            a3 += sH[half*4+3][i]*w;
        }
        sQ[half*4+0][j]=lrelu(a0);
        sQ[half*4+1][j]=lrelu(a1);
        sQ[half*4+2][j]=lrelu(a2);
        sQ[half*4+3][j]=lrelu(a3);
    }
    __syncthreads();
    int b = tid;
    {
        float accS[8] = {0,0,0,0,0,0,0,0};
        const float4* kk4 = (const float4*)(kk + (size_t)b*DD);
        for (int i4 = 0; i4 < DD/4; ++i4){
            float4 kv = kk4[i4];
            #pragma unroll
            for (int t = 0; t < 8; ++t){
                accS[t] += sQ[t][i4*4+0]*kv.x + sQ[t][i4*4+1]*kv.y
                         + sQ[t][i4*4+2]*kv.z + sQ[t][i4*4+3]*kv.w;
            }
        }
        #pragma unroll
        for (int t = 0; t < 8; ++t){
            float m = mask[(size_t)(n0+t)*NBB + b];
            sS[t][b] = m*accS[t] - 1000.f*(1.f-m);
        }
    }
    __syncthreads();
    int tg = tid >> 5, l = tid & 31;
    {
        float mx = -1e30f;
        for (int bb = l; bb < NBB; bb += 32) mx = fmaxf(mx, sS[tg][bb]);
        for (int o = 16; o > 0; o >>= 1) mx = fmaxf(mx, __shfl_xor(mx, o, 32));
        if (l == 0) sRed[tg] = mx;
    }
    __syncthreads();
    #pragma unroll
    for (int t = 0; t < 8; ++t) sS[t][b] = expf(sS[t][b] - sRed[t]);
    __syncthreads();
    {
        float sm = 0.f;
        for (int bb = l; bb < NBB; bb += 32) sm += sS[tg][bb];
        for (int o = 16; o > 0; o >>= 1) sm += __shfl_xor(sm, o, 32);
        if (l == 0) sSum[tg] = sm;
    }
    __syncthreads();
    {
        float accO[4] = {0,0,0,0};
        for (int bb = 0; bb < NBB; ++bb){
            float vvv = vv[(size_t)bb*DD + j];
            #pragma unroll
            for (int tt = 0; tt < 4; ++tt) accO[tt] += sS[half*4+tt][bb]*vvv;
        }
        #pragma unroll
        for (int tt = 0; tt < 4; ++tt){
            int t = half*4+tt;
            attnO[(size_t)(n0+t)*DD + j] = accO[tt] / sSum[t];
        }
    }
}

// ---------------- edge scatter: cnt, sum(rbf), sum(r), sum(rbf x r) at dst ----------------
__global__ __launch_bounds__(256) void k_edge(
    const int* __restrict__ src, const int* __restrict__ dst,
    const float* __restrict__ xA, const float* __restrict__ rbf_k,
    float* __restrict__ acc)
{
    int e = blockIdx.x*256 + threadIdx.x;
    if (e >= EE) return;
    int s = src[e], d = dst[e];
    float r0 = xA[s*3+0]-xA[d*3+0];
    float r1 = xA[s*3+1]-xA[d*3+1];
    float r2 = xA[s*3+2]-xA[d*3+2];
    float rn = sqrtf(r0*r0+r1*r1+r2*r2);
    float kc = rbf_k[0];
    float rb[RR];
    #pragma unroll
    for (int i = 0; i < RR; ++i){
        float df = rn - (float)i*CSPACE;
        rb[i] = expf(-df*df*kc);
    }
    float* base = acc + (size_t)d*64;
    atomicAdd(base, 1.f);
    #pragma unroll
    for (int i = 0; i < RR; ++i) atomicAdd(base+1+i, rb[i]);
    atomicAdd(base+16, r0); atomicAdd(base+17, r1); atomicAdd(base+18, r2);
    #pragma unroll
    for (int i = 0; i < RR; ++i){
        atomicAdd(base+19+i*3+0, rb[i]*r0);
        atomicAdd(base+19+i*3+1, rb[i]*r1);
        atomicAdd(base+19+i*3+2, rb[i]*r2);
    }
}

// ---------------- GRU (agg_h reconstructed inline) ----------------
__global__ __launch_bounds__(128) void k_gru(
    const float* __restrict__ hA, const float* __restrict__ attn,
    const float* __restrict__ hp, const float* __restrict__ acc,
    const float* __restrict__ Wr1, const float* __restrict__ br1,
    const float* __restrict__ WihT, const float* __restrict__ WhhT,
    const float* __restrict__ bih, const float* __restrict__ bhh,
    float* __restrict__ outNode)
{
    __shared__ float sX[8][2*DD];
    __shared__ float sG[8][DD];
    __shared__ float sA[8][16];
    int tid = threadIdx.x;
    int n0 = blockIdx.x*8;
    for (int i = tid; i < 8*16; i += 128) sA[i/16][i%16] = acc[(size_t)(n0 + i/16)*64 + (i%16)];
    for (int i = tid; i < 8*DD; i += 128) sX[i/DD][i%DD] = hA[(size_t)n0*DD + i];
    for (int i = tid; i < 8*DD; i += 128) sX[i/DD][DD + i%DD] = attn[(size_t)n0*DD + i];
    __syncthreads();
    int j = tid;
    #pragma unroll
    for (int t = 0; t < 8; ++t){
        float cnt = sA[t][0];
        float den = fmaxf(cnt, 1.f);
        float s = cnt*br1[j];
        #pragma unroll
        for (int r = 0; r < RR; ++r) s += sA[t][1+r]*Wr1[r*DD+j];
        sG[t][j] = hp[(size_t)(n0+t)*DD + j]*s/den;
    }
    __syncthreads();
    float aR[8]={0,0,0,0,0,0,0,0},aZ[8]={0,0,0,0,0,0,0,0};
    float aNi[8]={0,0,0,0,0,0,0,0},aNh[8]={0,0,0,0,0,0,0,0};
    for (int i = 0; i < 2*DD; ++i){
        float wr = WihT[i*384 + j];
        float wz = WihT[i*384 + DD + j];
        float wn = WihT[i*384 + 2*DD + j];
        #pragma unroll
        for (int t = 0; t < 8; ++t){
            float x = sX[t][i];
            aR[t] += x*wr; aZ[t] += x*wz; aNi[t] += x*wn;
        }
    }
    for (int i = 0; i < DD; ++i){
        float wr = WhhT[i*384 + j];
        float wz = WhhT[i*384 + DD + j];
        float wn = WhhT[i*384 + 2*DD + j];
        #pragma unroll
        for (int t = 0; t < 8; ++t){
            float x = sG[t][i];
            aR[t] += x*wr; aZ[t] += x*wz; aNh[t] += x*wn;
        }
    }
    float b_r = bih[j]+bhh[j];
    float b_z = bih[DD+j]+bhh[DD+j];
    float b_ni = bih[2*DD+j];
    float b_nh = bhh[2*DD+j];
    #pragma unroll
    for (int t = 0; t < 8; ++t){
        int n = n0+t;
        float r = sigmoidf_(aR[t]+b_r);
        float z = sigmoidf_(aZ[t]+b_z);
        float nn = tanhf(aNi[t]+b_ni + r*(aNh[t]+b_nh));
        float h = sX[t][j];
        outNode[(size_t)n*DD + j] = h + ((1.f-z)*nn + z*sG[t][j]);
    }
}

// ---------------- vector update: agg_v inline, VN-MLP, residual ----------------
__global__ __launch_bounds__(256) void k_vec(
    const float* __restrict__ vA, const float* __restrict__ vp,
    const float* __restrict__ hpp, const float* __restrict__ acc,
    const float* __restrict__ Wr2, const float* __restrict__ br2,
    const float* __restrict__ Wr3, const float* __restrict__ br3,
    const float* __restrict__ W1, const float* __restrict__ U1,
    const float* __restrict__ W2, float* __restrict__ outV)
{
    __shared__ float sW1[32*32], sU1[32*32], sW2[16*32];
    __shared__ float sWr2[RR*FF], sWr3[RR*FF];
    __shared__ float sVin[8][32][3];
    __shared__ float sVh[8][32][3];
    __shared__ float sAcc[8][64];
    __shared__ float sVA[8][48];
    int tid = threadIdx.x;
    for (int i = tid; i < 1024; i += 256){ sW1[i]=W1[i]; sU1[i]=U1[i]; }
    for (int i = tid; i < 512; i += 256) sW2[i]=W2[i];
    for (int i = tid; i < RR*FF; i += 256){ sWr2[i]=Wr2[i]; sWr3[i]=Wr3[i]; }
    int n0 = blockIdx.x*8;
    for (int i = tid; i < 8*64; i += 256) sAcc[i/64][i%64] = acc[(size_t)n0*64 + i];
    for (int i = tid; i < 8*48; i += 256) sVA[i/48][i%48] = vA[(size_t)n0*48 + i];
    __syncthreads();
    int t = tid >> 5, g = tid & 31;
    int n = n0 + t;
    if (g < 16){
        int f = g;
        float cnt = sAcc[t][0];
        float den = fmaxf(cnt, 1.f);
        float s1 = cnt*br2[f];
        #pragma unroll
        for (int r = 0; r < RR; ++r) s1 += sAcc[t][1+r]*sWr2[r*FF+f];
        float hpv = hpp[(size_t)n*FF+f];
        float b3 = br3[f];
        #pragma unroll
        for (int c = 0; c < 3; ++c){
            float s2 = b3*sAcc[t][16+c];
            #pragma unroll
            for (int r = 0; r < RR; ++r) s2 += sAcc[t][19+r*3+c]*sWr3[r*FF+f];
            float aggv = (vp[(size_t)n*48 + f*3 + c]*s1 + hpv*s2)/den;
            sVin[t][FF+f][c] = aggv;
            sVin[t][f][c] = sVA[t][f*3+c];
        }
    }
    __syncthreads();
    {
        float q0=0,q1=0,q2=0,k0=0,k1=0,k2=0;
        #pragma unroll
        for (int ff = 0; ff < 32; ++ff){
            int f = (ff + g) & 31;   // stagger
            float w = sW1[g*32+f], u = sU1[g*32+f];
            float v0=sVin[t][f][0], v1=sVin[t][f][1], v2=sVin[t][f][2];
            q0+=w*v0;q1+=w*v1;q2+=w*v2;
            k0+=u*v0;k1+=u*v1;k2+=u*v2;
        }
        float dot=q0*k0+q1*k1+q2*k2;
        float ksq=k0*k0+k1*k1+k2*k2+EPSV;
        float s = dot>=0.f?0.f:dot/ksq;
        sVh[t][g][0]=q0-s*k0; sVh[t][g][1]=q1-s*k1; sVh[t][g][2]=q2-s*k2;
    }
    __syncthreads();
    if (g < 16){
        float o0=sVA[t][g*3+0], o1=sVA[t][g*3+1], o2=sVA[t][g*3+2];
        #pragma unroll
        for (int ff = 0; ff < 32; ++ff){
            int f = (ff + g) & 31;   // stagger
            float w = sW2[g*32+f];
            o0 += w*sVh[t][f][0];
            o1 += w*sVh[t][f][1];
            o2 += w*sVh[t][f][2];
        }
        outV[(size_t)n*48 + g*3 + 0] = o0;
        outV[(size_t)n*48 + g*3 + 1] = o1;
        outV[(size_t)n*48 + g*3 + 2] = o2;
    }
}

extern "C" void kernel_launch(void* const* d_in, const int* in_sizes, int n_in,
                              void* d_out, int out_size, void* d_ws, size_t ws_size,
                              hipStream_t stream)
{
    const float* hA   = (const float*)d_in[0];
    const float* vA   = (const float*)d_in[1];
    const float* xA   = (const float*)d_in[2];
    const float* hB   = (const float*)d_in[3];
    const float* mask = (const float*)d_in[4];
    const int*   src  = (const int*)d_in[5];
    const int*   dst  = (const int*)d_in[6];
    const float* rbfk = (const float*)d_in[7];
    const float* Wr1  = (const float*)d_in[8];
    const float* br1  = (const float*)d_in[9];
    const float* Wr2  = (const float*)d_in[10];
    const float* br2  = (const float*)d_in[11];
    const float* Wr3  = (const float*)d_in[12];
    const float* br3  = (const float*)d_in[13];
    const float* vn1W = (const float*)d_in[14];
    const float* vn1U = (const float*)d_in[15];
    const float* vn2W = (const float*)d_in[16];
    const float* vn2U = (const float*)d_in[17];
    const float* vn3W = (const float*)d_in[18];
    const float* vn3U = (const float*)d_in[19];
    const float* phi1W= (const float*)d_in[20];
    const float* phi1b= (const float*)d_in[21];
    const float* phi2W= (const float*)d_in[22];
    const float* phi2b= (const float*)d_in[23];
    const float* phi3W= (const float*)d_in[24];
    const float* phi3b= (const float*)d_in[25];
    const float* Wq   = (const float*)d_in[26];
    const float* Wk   = (const float*)d_in[27];
    const float* Wv   = (const float*)d_in[28];
    const float* bv   = (const float*)d_in[29];
    const float* Wih  = (const float*)d_in[30];
    const float* Whh  = (const float*)d_in[31];
    const float* bih  = (const float*)d_in[32];
    const float* bhh  = (const float*)d_in[33];
    const float* W1   = (const float*)d_in[34];
    const float* U1   = (const float*)d_in[35];
    const float* W2   = (const float*)d_in[36];

    float* ws = (float*)d_ws;
    float* vnorm1 = ws;  ws += (size_t)NN*FF;
    float* hp     = ws;  ws += (size_t)NN*DD;
    float* hpp    = ws;  ws += (size_t)NN*FF;
    float* vp     = ws;  ws += (size_t)NN*FF*3;
    float* attn   = ws;  ws += (size_t)NN*DD;
    float* acc    = ws;  ws += (size_t)NN*64;
    float* kkB    = ws;  ws += (size_t)NBB*DD;
    float* vvB    = ws;  ws += (size_t)NBB*DD;
    float* WihT   = ws;  ws += (size_t)256*384;
    float* WhhT   = ws;  ws += (size_t)128*384;

    float* outV = (float*)d_out;
    float* outH = (float*)d_out + (size_t)NN*FF*3;

    hipMemsetAsync(acc, 0, (size_t)NN*64*sizeof(float), stream);
    k_transpose<<<384, 256, 0, stream>>>(Wih, Whh, WihT, WhhT);
    k_node_feats<<<NN/16, 256, 0, stream>>>(hA, vA, vn1W, vn1U, vn2W, vn2U, vn3W, vn3U,
                                            phi2W, phi2b, phi3W, phi3b, vnorm1, hpp, vp);
    k_hp<<<NN/8, 128, 0, stream>>>(hA, vnorm1, phi1W, phi1b, hp);
    k_kv<<<NBB, 128, 0, stream>>>(hB, Wk, Wv, bv, kkB, vvB);
    k_attn<<<NN/8, 256, 0, stream>>>(hA, Wq, kkB, vvB, mask, attn);
    k_edge<<<EE/256, 256, 0, stream>>>(src, dst, xA, rbfk, acc);
    k_gru<<<NN/8, 128, 0, stream>>>(hA, attn, hp, acc, Wr1, br1, WihT, WhhT, bih, bhh, outH);
    k_vec<<<NN/8, 256, 0, stream>>>(vA, vp, hpp, acc, Wr2, br2, Wr3, br3, W1, U1, W2, outV);
}

// Round 2
// 851.399 us; speedup vs baseline: 3.9953x; 3.9953x over previous
//
#include <hip/hip_runtime.h>
#include <math.h>

#define NN 50000
#define NBB 256
#define DD 128
#define FF 16
#define EE 800000
#define RR 15
#define EPSV 1e-7f
#define CSPACE (5.0f/14.0f)

__device__ __forceinline__ float lrelu(float x){ return x >= 0.f ? x : 0.01f*x; }
__device__ __forceinline__ float sigmoidf_(float x){ return 1.f/(1.f+expf(-x)); }

// ---------------- transpose GRU weights for coalesced GEMV ----------------
__global__ void k_transpose(const float* __restrict__ Wih, const float* __restrict__ Whh,
                            float* __restrict__ WihT, float* __restrict__ WhhT){
    int i = blockIdx.x*256 + threadIdx.x;
    if (i < 384*256){ int k = i/256, j = i%256; WihT[j*384+k] = Wih[i]; }
    if (i < 384*128){ int k = i/128, j = i%128; WhhT[j*384+k] = Whh[i]; }
}

// ---------------- per-node: VN1/VN2/VN3 norms, phi3 gate -> vp, phi2 -> hpp ----------------
__global__ __launch_bounds__(256) void k_node_feats(
    const float* __restrict__ hA, const float* __restrict__ vA,
    const float* __restrict__ vn1W, const float* __restrict__ vn1U,
    const float* __restrict__ vn2W, const float* __restrict__ vn2U,
    const float* __restrict__ vn3W, const float* __restrict__ vn3U,
    const float* __restrict__ phi2W, const float* __restrict__ phi2b,
    const float* __restrict__ phi3W, const float* __restrict__ phi3b,
    float* __restrict__ vnorm1O, float* __restrict__ hppO, float* __restrict__ vpO)
{
    __shared__ float sVn[6][FF*FF];
    __shared__ float sP3[DD*FF];
    __shared__ float sP2[(DD+FF)*FF];
    __shared__ float sV[16][50];        // padded
    __shared__ float sH[16][DD+2];      // padded
    __shared__ float sVn2[16][FF];
    int tid = threadIdx.x;
    for (int i = tid; i < FF*FF; i += 256){
        sVn[0][i]=vn1W[i]; sVn[1][i]=vn1U[i]; sVn[2][i]=vn2W[i];
        sVn[3][i]=vn2U[i]; sVn[4][i]=vn3W[i]; sVn[5][i]=vn3U[i];
    }
    for (int i = tid; i < DD*FF; i += 256) sP3[i]=phi3W[i];
    for (int i = tid; i < (DD+FF)*FF; i += 256) sP2[i]=phi2W[i];
    int n0 = blockIdx.x*16;
    for (int i = tid; i < 16*FF*3; i += 256) sV[i/(FF*3)][i%(FF*3)] = vA[(size_t)n0*FF*3 + i];
    for (int i = tid; i < 16*DD; i += 256) sH[i/DD][i%DD] = hA[(size_t)n0*DD + i];
    __syncthreads();
    int t = tid >> 4, g = tid & 15;
    int n = n0 + t;
    const float* v = sV[t];
    float o0=0.f,o1=0.f,o2=0.f;
    float vn_norm0=0.f, vn_norm1v=0.f;
    #pragma unroll
    for (int m = 0; m < 3; ++m){
        const float* W = sVn[2*m]; const float* U = sVn[2*m+1];
        float q0=0,q1=0,q2=0,k0=0,k1=0,k2=0;
        #pragma unroll
        for (int ff = 0; ff < FF; ++ff){
            int f = (ff + g) & (FF-1);   // stagger to avoid LDS bank conflict
            float w = W[g*FF+f], u = U[g*FF+f];
            float v0=v[f*3],v1=v[f*3+1],v2=v[f*3+2];
            q0+=w*v0; q1+=w*v1; q2+=w*v2;
            k0+=u*v0; k1+=u*v1; k2+=u*v2;
        }
        float dot=q0*k0+q1*k1+q2*k2;
        float ksq=k0*k0+k1*k1+k2*k2+EPSV;
        float s = dot>=0.f?0.f:dot/ksq;
        o0=q0-s*k0; o1=q1-s*k1; o2=q2-s*k2;
        if (m==0) vn_norm0 = sqrtf(o0*o0+o1*o1+o2*o2) + EPSV;
        if (m==1) vn_norm1v = sqrtf(o0*o0+o1*o1+o2*o2) + EPSV;
    }
    vnorm1O[(size_t)n*FF+g] = vn_norm0;
    sVn2[t][g] = vn_norm1v;
    __syncthreads();
    float acc3 = phi3b[g];
    for (int i = 0; i < DD; ++i) acc3 += sH[t][i]*sP3[i*FF+g];
    float gate = lrelu(acc3);
    vpO[(size_t)n*FF*3 + g*3 + 0] = o0*gate;
    vpO[(size_t)n*FF*3 + g*3 + 1] = o1*gate;
    vpO[(size_t)n*FF*3 + g*3 + 2] = o2*gate;
    float acc2 = phi2b[g];
    for (int i = 0; i < DD; ++i) acc2 += sH[t][i]*sP2[i*FF+g];
    #pragma unroll
    for (int f = 0; f < FF; ++f) acc2 += sVn2[t][f]*sP2[(DD+f)*FF+g];
    hppO[(size_t)n*FF+g] = lrelu(acc2);
}

// ---------------- hp = lrelu([h_A, vnorm1] @ phi1_W + b) ----------------
__global__ __launch_bounds__(128) void k_hp(
    const float* __restrict__ hA, const float* __restrict__ vnorm1,
    const float* __restrict__ phi1W, const float* __restrict__ phi1b,
    float* __restrict__ hpO)
{
    __shared__ float sX[8][DD+FF];
    int tid = threadIdx.x;
    int n0 = blockIdx.x*8;
    for (int i = tid; i < 8*DD; i += 128) sX[i/DD][i%DD] = hA[(size_t)n0*DD + i];
    for (int i = tid; i < 8*FF; i += 128) sX[i/FF][DD + i%FF] = vnorm1[(size_t)n0*FF + i];
    __syncthreads();
    float b = phi1b[tid];
    float a[8];
    #pragma unroll
    for (int t = 0; t < 8; ++t) a[t] = b;
    for (int i = 0; i < DD+FF; ++i){
        float w = phi1W[i*DD + tid];
        #pragma unroll
        for (int t = 0; t < 8; ++t) a[t] += sX[t][i]*w;
    }
    #pragma unroll
    for (int t = 0; t < 8; ++t) hpO[(size_t)(n0+t)*DD+tid] = lrelu(a[t]);
}

// ---------------- kk = lrelu(h_B@Wk), vv = h_B@Wv + bv ----------------
__global__ __launch_bounds__(128) void k_kv(
    const float* __restrict__ hB, const float* __restrict__ Wk,
    const float* __restrict__ Wv, const float* __restrict__ bv,
    float* __restrict__ kkO, float* __restrict__ vvO)
{
    __shared__ float sB[DD];
    int b = blockIdx.x, j = threadIdx.x;
    sB[j] = hB[(size_t)b*DD + j];
    __syncthreads();
    float ak = 0.f, av = bv[j];
    for (int i = 0; i < DD; ++i){
        float h = sB[i];
        ak += h*Wk[i*DD+j];
        av += h*Wv[i*DD+j];
    }
    kkO[(size_t)b*DD+j] = lrelu(ak);
    vvO[(size_t)b*DD+j] = av;
}

// ---------------- fused cross-attention: q-proj, scores, softmax, PV ----------------
__global__ __launch_bounds__(256) void k_attn(
    const float* __restrict__ hA, const float* __restrict__ Wq,
    const float* __restrict__ kk, const float* __restrict__ vv,
    const float* __restrict__ mask, float* __restrict__ attnO)
{
    __shared__ float sH[8][DD];
    __shared__ float sQ[8][DD];
    __shared__ float sS[8][NBB];
    __shared__ float sRed[8];
    __shared__ float sSum[8];
    int tid = threadIdx.x;
    int n0 = blockIdx.x*8;
    for (int i = tid; i < 8*DD; i += 256) sH[i/DD][i%DD] = hA[(size_t)n0*DD + i];
    __syncthreads();
    int j = tid & 127, half = tid >> 7;
    {
        float a0=0,a1=0,a2=0,a3=0;
        for (int i = 0; i < DD; ++i){
            float w = Wq[i*DD+j];
            a0 += sH[half*4+0][i]*w;
            a1 += sH[half*4+1][i]*w;
            a2 += sH[half*4+2][i]*w;
            a3 += sH[half*4+3][i]*w;
        }
        sQ[half*4+0][j]=lrelu(a0);
        sQ[half*4+1][j]=lrelu(a1);
        sQ[half*4+2][j]=lrelu(a2);
        sQ[half*4+3][j]=lrelu(a3);
    }
    __syncthreads();
    int b = tid;
    {
        float accS[8] = {0,0,0,0,0,0,0,0};
        const float4* kk4 = (const float4*)(kk + (size_t)b*DD);
        for (int i4 = 0; i4 < DD/4; ++i4){
            float4 kv = kk4[i4];
            #pragma unroll
            for (int t = 0; t < 8; ++t){
                accS[t] += sQ[t][i4*4+0]*kv.x + sQ[t][i4*4+1]*kv.y
                         + sQ[t][i4*4+2]*kv.z + sQ[t][i4*4+3]*kv.w;
            }
        }
        #pragma unroll
        for (int t = 0; t < 8; ++t){
            float m = mask[(size_t)(n0+t)*NBB + b];
            sS[t][b] = m*accS[t] - 1000.f*(1.f-m);
        }
    }
    __syncthreads();
    int tg = tid >> 5, l = tid & 31;
    {
        float mx = -1e30f;
        for (int bb = l; bb < NBB; bb += 32) mx = fmaxf(mx, sS[tg][bb]);
        for (int o = 16; o > 0; o >>= 1) mx = fmaxf(mx, __shfl_xor(mx, o, 32));
        if (l == 0) sRed[tg] = mx;
    }
    __syncthreads();
    #pragma unroll
    for (int t = 0; t < 8; ++t) sS[t][b] = expf(sS[t][b] - sRed[t]);
    __syncthreads();
    {
        float sm = 0.f;
        for (int bb = l; bb < NBB; bb += 32) sm += sS[tg][bb];
        for (int o = 16; o > 0; o >>= 1) sm += __shfl_xor(sm, o, 32);
        if (l == 0) sSum[tg] = sm;
    }
    __syncthreads();
    {
        float accO[4] = {0,0,0,0};
        for (int bb = 0; bb < NBB; ++bb){
            float vvv = vv[(size_t)bb*DD + j];
            #pragma unroll
            for (int tt = 0; tt < 4; ++tt) accO[tt] += sS[half*4+tt][bb]*vvv;
        }
        #pragma unroll
        for (int tt = 0; tt < 4; ++tt){
            int t = half*4+tt;
            attnO[(size_t)(n0+t)*DD + j] = accO[tt] / sSum[t];
        }
    }
}

// ---------------- edge phase: counting sort by dst, then per-node gather ----------------
__global__ __launch_bounds__(256) void k_hist(const int* __restrict__ dst, int* __restrict__ deg){
    int e = blockIdx.x*256 + threadIdx.x;
    if (e < EE) atomicAdd(&deg[dst[e]], 1);
}

__global__ __launch_bounds__(256) void k_scan1(const int* __restrict__ deg,
                                               int* __restrict__ excl, int* __restrict__ bsum){
    __shared__ int s[256];
    int tid = threadIdx.x;
    int i = blockIdx.x*256 + tid;
    int v = (i < NN) ? deg[i] : 0;
    s[tid] = v;
    __syncthreads();
    for (int o = 1; o < 256; o <<= 1){
        int t = 0;
        if (tid >= o) t = s[tid-o];
        __syncthreads();
        if (tid >= o) s[tid] += t;
        __syncthreads();
    }
    if (i < NN) excl[i] = s[tid] - v;
    if (tid == 255) bsum[blockIdx.x] = s[255];
}

__global__ __launch_bounds__(256) void k_scan2(const int* __restrict__ bsum,
                                               int* __restrict__ boff, int nb){
    __shared__ int s[256];
    int tid = threadIdx.x;
    int v = (tid < nb) ? bsum[tid] : 0;
    s[tid] = v;
    __syncthreads();
    for (int o = 1; o < 256; o <<= 1){
        int t = 0;
        if (tid >= o) t = s[tid-o];
        __syncthreads();
        if (tid >= o) s[tid] += t;
        __syncthreads();
    }
    if (tid < nb) boff[tid] = s[tid] - v;
}

__global__ __launch_bounds__(256) void k_scan3(const int* __restrict__ excl,
                                               const int* __restrict__ boff,
                                               int* __restrict__ start, int* __restrict__ cursor){
    int i = blockIdx.x*256 + threadIdx.x;
    if (i < NN){
        int st = excl[i] + boff[blockIdx.x];
        start[i] = st;
        cursor[i] = st;
    }
    if (i == 0) start[NN] = EE;
}

__global__ __launch_bounds__(256) void k_scatter(const int* __restrict__ src,
                                                 const int* __restrict__ dst,
                                                 int* __restrict__ cursor, int* __restrict__ esrc){
    int e = blockIdx.x*256 + threadIdx.x;
    if (e >= EE) return;
    int pos = atomicAdd(&cursor[dst[e]], 1);
    esrc[pos] = src[e];
}

__global__ __launch_bounds__(256) void k_gather(const int* __restrict__ start,
                                                const int* __restrict__ esrc,
                                                const float* __restrict__ xA,
                                                const float* __restrict__ rbf_k,
                                                float* __restrict__ acc)
{
    int n = blockIdx.x*256 + threadIdx.x;
    if (n >= NN) return;
    float kc = rbf_k[0];
    float xd0 = xA[n*3+0], xd1 = xA[n*3+1], xd2 = xA[n*3+2];
    float a[64];
    #pragma unroll
    for (int i = 0; i < 64; ++i) a[i] = 0.f;
    int b0 = start[n], b1 = start[n+1];
    for (int i = b0; i < b1; ++i){
        int s = esrc[i];
        float r0 = xA[s*3+0]-xd0, r1 = xA[s*3+1]-xd1, r2 = xA[s*3+2]-xd2;
        float rn = sqrtf(r0*r0+r1*r1+r2*r2);
        a[0] += 1.f;
        a[16] += r0; a[17] += r1; a[18] += r2;
        #pragma unroll
        for (int q = 0; q < RR; ++q){
            float df = rn - (float)q*CSPACE;
            float rb = expf(-df*df*kc);
            a[1+q] += rb;
            a[19+q*3+0] += rb*r0;
            a[19+q*3+1] += rb*r1;
            a[19+q*3+2] += rb*r2;
        }
    }
    float4* o = (float4*)(acc + (size_t)n*64);
    #pragma unroll
    for (int i = 0; i < 16; ++i) o[i] = make_float4(a[4*i], a[4*i+1], a[4*i+2], a[4*i+3]);
}

// ---------------- GRU (agg_h reconstructed inline) ----------------
__global__ __launch_bounds__(128) void k_gru(
    const float* __restrict__ hA, const float* __restrict__ attn,
    const float* __restrict__ hp, const float* __restrict__ acc,
    const float* __restrict__ Wr1, const float* __restrict__ br1,
    const float* __restrict__ WihT, const float* __restrict__ WhhT,
    const float* __restrict__ bih, const float* __restrict__ bhh,
    float* __restrict__ outNode)
{
    __shared__ float sX[8][2*DD];
    __shared__ float sG[8][DD];
    __shared__ float sA[8][16];
    int tid = threadIdx.x;
    int n0 = blockIdx.x*8;
    for (int i = tid; i < 8*16; i += 128) sA[i/16][i%16] = acc[(size_t)(n0 + i/16)*64 + (i%16)];
    for (int i = tid; i < 8*DD; i += 128) sX[i/DD][i%DD] = hA[(size_t)n0*DD + i];
    for (int i = tid; i < 8*DD; i += 128) sX[i/DD][DD + i%DD] = attn[(size_t)n0*DD + i];
    __syncthreads();
    int j = tid;
    #pragma unroll
    for (int t = 0; t < 8; ++t){
        float cnt = sA[t][0];
        float den = fmaxf(cnt, 1.f);
        float s = cnt*br1[j];
        #pragma unroll
        for (int r = 0; r < RR; ++r) s += sA[t][1+r]*Wr1[r*DD+j];
        sG[t][j] = hp[(size_t)(n0+t)*DD + j]*s/den;
    }
    __syncthreads();
    float aR[8]={0,0,0,0,0,0,0,0},aZ[8]={0,0,0,0,0,0,0,0};
    float aNi[8]={0,0,0,0,0,0,0,0},aNh[8]={0,0,0,0,0,0,0,0};
    for (int i = 0; i < 2*DD; ++i){
        float wr = WihT[i*384 + j];
        float wz = WihT[i*384 + DD + j];
        float wn = WihT[i*384 + 2*DD + j];
        #pragma unroll
        for (int t = 0; t < 8; ++t){
            float x = sX[t][i];
            aR[t] += x*wr; aZ[t] += x*wz; aNi[t] += x*wn;
        }
    }
    for (int i = 0; i < DD; ++i){
        float wr = WhhT[i*384 + j];
        float wz = WhhT[i*384 + DD + j];
        float wn = WhhT[i*384 + 2*DD + j];
        #pragma unroll
        for (int t = 0; t < 8; ++t){
            float x = sG[t][i];
            aR[t] += x*wr; aZ[t] += x*wz; aNh[t] += x*wn;
        }
    }
    float b_r = bih[j]+bhh[j];
    float b_z = bih[DD+j]+bhh[DD+j];
    float b_ni = bih[2*DD+j];
    float b_nh = bhh[2*DD+j];
    #pragma unroll
    for (int t = 0; t < 8; ++t){
        int n = n0+t;
        float r = sigmoidf_(aR[t]+b_r);
        float z = sigmoidf_(aZ[t]+b_z);
        float nn = tanhf(aNi[t]+b_ni + r*(aNh[t]+b_nh));
        float h = sX[t][j];
        outNode[(size_t)n*DD + j] = h + ((1.f-z)*nn + z*sG[t][j]);
    }
}

// ---------------- vector update: agg_v inline, VN-MLP, residual ----------------
__global__ __launch_bounds__(256) void k_vec(
    const float* __restrict__ vA, const float* __restrict__ vp,
    const float* __restrict__ hpp, const float* __restrict__ acc,
    const float* __restrict__ Wr2, const float* __restrict__ br2,
    const float* __restrict__ Wr3, const float* __restrict__ br3,
    const float* __restrict__ W1, const float* __restrict__ U1,
    const float* __restrict__ W2, float* __restrict__ outV)
{
    __shared__ float sW1[32*32], sU1[32*32], sW2[16*32];
    __shared__ float sWr2[RR*FF], sWr3[RR*FF];
    __shared__ float sVin[8][32][3];
    __shared__ float sVh[8][32][3];
    __shared__ float sAcc[8][64];
    __shared__ float sVA[8][48];
    int tid = threadIdx.x;
    for (int i = tid; i < 1024; i += 256){ sW1[i]=W1[i]; sU1[i]=U1[i]; }
    for (int i = tid; i < 512; i += 256) sW2[i]=W2[i];
    for (int i = tid; i < RR*FF; i += 256){ sWr2[i]=Wr2[i]; sWr3[i]=Wr3[i]; }
    int n0 = blockIdx.x*8;
    for (int i = tid; i < 8*64; i += 256) sAcc[i/64][i%64] = acc[(size_t)n0*64 + i];
    for (int i = tid; i < 8*48; i += 256) sVA[i/48][i%48] = vA[(size_t)n0*48 + i];
    __syncthreads();
    int t = tid >> 5, g = tid & 31;
    int n = n0 + t;
    if (g < 16){
        int f = g;
        float cnt = sAcc[t][0];
        float den = fmaxf(cnt, 1.f);
        float s1 = cnt*br2[f];
        #pragma unroll
        for (int r = 0; r < RR; ++r) s1 += sAcc[t][1+r]*sWr2[r*FF+f];
        float hpv = hpp[(size_t)n*FF+f];
        float b3 = br3[f];
        #pragma unroll
        for (int c = 0; c < 3; ++c){
            float s2 = b3*sAcc[t][16+c];
            #pragma unroll
            for (int r = 0; r < RR; ++r) s2 += sAcc[t][19+r*3+c]*sWr3[r*FF+f];
            float aggv = (vp[(size_t)n*48 + f*3 + c]*s1 + hpv*s2)/den;
            sVin[t][FF+f][c] = aggv;
            sVin[t][f][c] = sVA[t][f*3+c];
        }
    }
    __syncthreads();
    {
        float q0=0,q1=0,q2=0,k0=0,k1=0,k2=0;
        #pragma unroll
        for (int ff = 0; ff < 32; ++ff){
            int f = (ff + g) & 31;   // stagger
            float w = sW1[g*32+f], u = sU1[g*32+f];
            float v0=sVin[t][f][0], v1=sVin[t][f][1], v2=sVin[t][f][2];
            q0+=w*v0;q1+=w*v1;q2+=w*v2;
            k0+=u*v0;k1+=u*v1;k2+=u*v2;
        }
        float dot=q0*k0+q1*k1+q2*k2;
        float ksq=k0*k0+k1*k1+k2*k2+EPSV;
        float s = dot>=0.f?0.f:dot/ksq;
        sVh[t][g][0]=q0-s*k0; sVh[t][g][1]=q1-s*k1; sVh[t][g][2]=q2-s*k2;
    }
    __syncthreads();
    if (g < 16){
        float o0=sVA[t][g*3+0], o1=sVA[t][g*3+1], o2=sVA[t][g*3+2];
        #pragma unroll
        for (int ff = 0; ff < 32; ++ff){
            int f = (ff + g) & 31;   // stagger
            float w = sW2[g*32+f];
            o0 += w*sVh[t][f][0];
            o1 += w*sVh[t][f][1];
            o2 += w*sVh[t][f][2];
        }
        outV[(size_t)n*48 + g*3 + 0] = o0;
        outV[(size_t)n*48 + g*3 + 1] = o1;
        outV[(size_t)n*48 + g*3 + 2] = o2;
    }
}

extern "C" void kernel_launch(void* const* d_in, const int* in_sizes, int n_in,
                              void* d_out, int out_size, void* d_ws, size_t ws_size,
                              hipStream_t stream)
{
    const float* hA   = (const float*)d_in[0];
    const float* vA   = (const float*)d_in[1];
    const float* xA   = (const float*)d_in[2];
    const float* hB   = (const float*)d_in[3];
    const float* mask = (const float*)d_in[4];
    const int*   src  = (const int*)d_in[5];
    const int*   dst  = (const int*)d_in[6];
    const float* rbfk = (const float*)d_in[7];
    const float* Wr1  = (const float*)d_in[8];
    const float* br1  = (const float*)d_in[9];
    const float* Wr2  = (const float*)d_in[10];
    const float* br2  = (const float*)d_in[11];
    const float* Wr3  = (const float*)d_in[12];
    const float* br3  = (const float*)d_in[13];
    const float* vn1W = (const float*)d_in[14];
    const float* vn1U = (const float*)d_in[15];
    const float* vn2W = (const float*)d_in[16];
    const float* vn2U = (const float*)d_in[17];
    const float* vn3W = (const float*)d_in[18];
    const float* vn3U = (const float*)d_in[19];
    const float* phi1W= (const float*)d_in[20];
    const float* phi1b= (const float*)d_in[21];
    const float* phi2W= (const float*)d_in[22];
    const float* phi2b= (const float*)d_in[23];
    const float* phi3W= (const float*)d_in[24];
    const float* phi3b= (const float*)d_in[25];
    const float* Wq   = (const float*)d_in[26];
    const float* Wk   = (const float*)d_in[27];
    const float* Wv   = (const float*)d_in[28];
    const float* bv   = (const float*)d_in[29];
    const float* Wih  = (const float*)d_in[30];
    const float* Whh  = (const float*)d_in[31];
    const float* bih  = (const float*)d_in[32];
    const float* bhh  = (const float*)d_in[33];
    const float* W1   = (const float*)d_in[34];
    const float* U1   = (const float*)d_in[35];
    const float* W2   = (const float*)d_in[36];

    float* ws = (float*)d_ws;
    float* vnorm1 = ws;  ws += (size_t)NN*FF;
    float* hp     = ws;  ws += (size_t)NN*DD;
    float* hpp    = ws;  ws += (size_t)NN*FF;
    float* vp     = ws;  ws += (size_t)NN*FF*3;
    float* attn   = ws;  ws += (size_t)NN*DD;
    float* acc    = ws;  ws += (size_t)NN*64;
    float* kkB    = ws;  ws += (size_t)NBB*DD;
    float* vvB    = ws;  ws += (size_t)NBB*DD;
    float* WihT   = ws;  ws += (size_t)256*384;
    float* WhhT   = ws;  ws += (size_t)128*384;
    int* deg    = (int*)ws;  ws += NN;
    int* excl   = (int*)ws;  ws += NN;
    int* bsum   = (int*)ws;  ws += 256;
    int* boff   = (int*)ws;  ws += 256;
    int* startN = (int*)ws;  ws += NN+1;
    int* cursor = (int*)ws;  ws += NN;
    int* esrc   = (int*)ws;  ws += EE;

    float* outV = (float*)d_out;
    float* outH = (float*)d_out + (size_t)NN*FF*3;

    const int NB_SCAN = (NN + 255)/256;   // 196

    hipMemsetAsync(deg, 0, (size_t)NN*sizeof(int), stream);
    k_transpose<<<384, 256, 0, stream>>>(Wih, Whh, WihT, WhhT);
    k_hist<<<(EE+255)/256, 256, 0, stream>>>(dst, deg);
    k_scan1<<<NB_SCAN, 256, 0, stream>>>(deg, excl, bsum);
    k_scan2<<<1, 256, 0, stream>>>(bsum, boff, NB_SCAN);
    k_scan3<<<NB_SCAN, 256, 0, stream>>>(excl, boff, startN, cursor);
    k_scatter<<<(EE+255)/256, 256, 0, stream>>>(src, dst, cursor, esrc);
    k_gather<<<(NN+255)/256, 256, 0, stream>>>(startN, esrc, xA, rbfk, acc);
    k_node_feats<<<NN/16, 256, 0, stream>>>(hA, vA, vn1W, vn1U, vn2W, vn2U, vn3W, vn3U,
                                            phi2W, phi2b, phi3W, phi3b, vnorm1, hpp, vp);
    k_hp<<<NN/8, 128, 0, stream>>>(hA, vnorm1, phi1W, phi1b, hp);
    k_kv<<<NBB, 128, 0, stream>>>(hB, Wk, Wv, bv, kkB, vvB);
    k_attn<<<NN/8, 256, 0, stream>>>(hA, Wq, kkB, vvB, mask, attn);
    k_gru<<<NN/8, 128, 0, stream>>>(hA, attn, hp, acc, Wr1, br1, WihT, WhhT, bih, bhh, outH);
    k_vec<<<NN/8, 256, 0, stream>>>(vA, vp, hpp, acc, Wr2, br2, Wr3, br3, W1, U1, W2, outV);
}